// Round 3
// baseline (122.430 us; speedup 1.0000x reference)
//
#include <hip/hip_runtime.h>
#include <stdint.h>

typedef unsigned long long u64;

static constexpr int T = 1024;
static constexpr int B = 2;
static constexpr int N = 10000;
static constexpr int L = 30;
static constexpr int S = 2 * L + 1;   // 61

static constexpr int NBLK  = 2048;    // == B*T: every block sweeps AND corrects one (b,t) pair
static constexpr int CHUNK = 2500;    // float4 per block; 2048*2500 == 5,120,000 == T*B*N/4
static constexpr int TAIL  = CHUNK - 9 * 256;   // 196

static constexpr u64 ALL   = (1ULL << S) - 1;
static constexpr u64 EVENM = 0x5555555555555555ULL & ((1ULL << S) - 1);

__device__ __forceinline__ float block_reduce(float s) {
    for (int off = 32; off; off >>= 1) s += __shfl_down(s, off, 64);
    __shared__ float tmp[4];
    int lane = threadIdx.x & 63, w = threadIdx.x >> 6;
    if (lane == 0) tmp[w] = s;
    __syncthreads();
    float t = 0.f;
    if (threadIdx.x == 0)
        for (int i = 0; i < 4; ++i) t += tmp[i];
    return t;
}

__device__ __forceinline__ float sq4(float4 v) {
    return v.x * v.x + v.y * v.y + v.z * v.z + v.w * v.w;
}

// Uniform-work version: all 2048 blocks sweep one contiguous 2500-float4 chunk,
// AND each block computes the CTC-lattice correction for exactly ONE (b,t) pair
// (pair == blockIdx.x), in warp 0 only, via shuffles — no LDS, no __syncthreads
// in the corr path. Corr ALU work is placed between sweep-load issue and
// consume so it hides under the in-flight global loads. Every block has an
// identical profile -> no straggler tail from the old blocks-0..255 corr split.
__global__ void k_fused(const float4* __restrict__ x4, const float* __restrict__ x,
                        const int* __restrict__ label, float* __restrict__ partials) {
    int tid = threadIdx.x;
    float s = 0.f;

    // ---- sweep batch 1: issue 5 independent loads ----
    const float4* p = x4 + (size_t)blockIdx.x * CHUNK + tid;
    float4 v0 = p[0 * 256];
    float4 v1 = p[1 * 256];
    float4 v2 = p[2 * 256];
    float4 v3 = p[3 * 256];
    float4 v4 = p[4 * 256];

    // ---- corr for pair = blockIdx.x (b = pair>>10, t = pair&1023), warp 0 ----
    if (tid < 32) {
        int lane = tid;                    // 0..31; lanes 0..L-1 carry labels
        int b = blockIdx.x >> 10;
        int t = blockIdx.x & (T - 1);
        int myl = (lane < L) ? label[b * L + lane] : 0;   // real labels are >= 1

        // Block-uniform Af/Ab + per-lane dup mask, one 30-iter shuffle loop.
        u64 Af = 0, Ab = 0, dup = 0;
        int prev = -1;
        #pragma unroll
        for (int k2 = 0; k2 < L; ++k2) {
            int lk = __shfl(myl, k2, 64);
            u64 bitk = 1ULL << (2 * k2 + 1);
            if (k2 == 0) {
                Af |= bitk;
            } else if (lk != prev) {
                Af |= bitk;                          // lb[k2] != lb[k2-1]
                Ab |= 1ULL << (2 * (k2 - 1) + 1);    // lb[k2-1] != lb[k2]
            }
            if (lk == myl && k2 < lane) dup |= bitk;
            prev = lk;
        }
        Ab |= 1ULL << (2 * (L - 1) + 1);

        // Reachability mask (block-uniform branch; 1792/2048 blocks skip loops).
        u64 m;
        if (t < 64) {
            // backward map saturated (t <= T-61); forward needs t steps
            u64 c = 3ULL;
            for (int i = 0; i < t; ++i) c = (c | (c << 1) | ((c << 2) & Af)) & ALL;
            m = c;
        } else if (t >= T - 64) {
            // forward map saturated (t >= 60); backward needs T-1-t steps
            u64 c = (1ULL << (S - 1)) | (1ULL << (S - 2));
            int n = T - 1 - t;
            for (int i = 0; i < n; ++i) c = c | (c >> 1) | ((c >> 2) & Ab);
            m = c;
        } else {
            m = ALL;
        }

        const float* row = x + (size_t)t * (B * N) + (size_t)b * N;
        if (lane < L) {
            u64 bit = 1ULL << (2 * lane + 1);
            if ((m & bit) && !(m & dup)) {
                float vv = row[myl];
                s -= vv * vv;
            }
        } else if (lane == L) {
            if (m & EVENM) { float vv = row[0]; s -= vv * vv; }  // blank, once
        }
    }

    // ---- consume batch 1, issue+consume batch 2 (196-thread predicated tail) ----
    s += sq4(v0); s += sq4(v1); s += sq4(v2); s += sq4(v3); s += sq4(v4);
    v0 = p[5 * 256];
    v1 = p[6 * 256];
    v2 = p[7 * 256];
    v3 = p[8 * 256];
    v4 = (tid < TAIL) ? p[9 * 256] : make_float4(0.f, 0.f, 0.f, 0.f);
    s += sq4(v0); s += sq4(v1); s += sq4(v2); s += sq4(v3); s += sq4(v4);

    float tot = block_reduce(s);
    if (threadIdx.x == 0) partials[blockIdx.x] = tot;
}

// out = 0.5 * sum(partials)
__global__ void k_final(const float* __restrict__ partials, float* __restrict__ out) {
    float s = 0.f;
    for (int i = threadIdx.x; i < NBLK; i += 256) s += partials[i];
    float tot = block_reduce(s);
    if (threadIdx.x == 0) out[0] = 0.5f * tot;
}

extern "C" void kernel_launch(void* const* d_in, const int* in_sizes, int n_in,
                              void* d_out, int out_size, void* d_ws, size_t ws_size,
                              hipStream_t stream) {
    const float* logits = (const float*)d_in[0];
    const int*   label  = (const int*)d_in[2];
    float* partials = (float*)d_ws;

    k_fused<<<NBLK, 256, 0, stream>>>((const float4*)logits, logits, label, partials);
    k_final<<<1, 256, 0, stream>>>(partials, (float*)d_out);
}